// Round 3
// baseline (115.184 us; speedup 1.0000x reference)
//
#include <hip/hip_runtime.h>

// Deformable conv (K=3, stride=1, pad=1, dil=1), N=8, Cin=Cout=128, H=W=64.
// v4: - wts LDS tile REMOVED: per-wave B-fragments load straight from global wt into a
//       double-buffered VGPR bank (8 x b128 per kk), issued in the pre-phase and pinned
//       above the MFMAs by sched_barrier(0) (v3's proven gv pattern; round-1 lacked the pin).
//       LDS traffic/kk drops 256KB -> 160KB per 2-row-equivalent; LDS size 139KB -> 69.6KB.
//     - blocks now 256 thr / 4 waves, one (n,ho) row each; 2 blocks/CU -> barrier scope halved.
//     - XCD swizzle: n = bid&7 -> each XCD owns one image (xt 2MB + offs 1.2MB + wt 0.3MB
//       fits its 4MB L2). prep_all produces xt with the same mapping.
//     - v_cvt_pk_bf16_f32 replaces the 10-op manual RNE pack in blend + prep phase 2.
// ws usage: xt = 8 MB at ws+0, wt = 288 KB at ws+8388608. Fully rewritten each launch.

#define H  64
#define W  64
#define CIN 128
#define COUT 128
#define NB 8
#define KK 9
#define SROW (CIN + 8)

typedef short bf16x8 __attribute__((ext_vector_type(8)));
typedef float f32x4  __attribute__((ext_vector_type(4)));

__device__ __forceinline__ unsigned short f2bf(float f) {
    unsigned u = __builtin_bit_cast(unsigned, f);
    u += 0x7FFFu + ((u >> 16) & 1u);          // round-nearest-even
    return (unsigned short)(u >> 16);
}
__device__ __forceinline__ unsigned cvt_pk_bf16(float lo, float hi) {
    unsigned r;
    asm("v_cvt_pk_bf16_f32 %0, %1, %2" : "=v"(r) : "v"(lo), "v"(hi));
    return r;                                  // low16 = bf16(lo), high16 = bf16(hi), RNE
}
__device__ __forceinline__ float lo_f(unsigned u) { return __builtin_bit_cast(float, u << 16); }
__device__ __forceinline__ float hi_f(unsigned u) { return __builtin_bit_cast(float, u & 0xFFFF0000u); }

// Merged prep: blocks [0, NB*H) transpose x (NCHW fp32 -> NHWC bf16), XCD-local (n = b&7);
// blocks [NB*H, NB*H+576) convert weight fp32 [co][c][kk] -> bf16 [kk][co][c].
__global__ void prep_all(const float* __restrict__ x, const float* __restrict__ w,
                         unsigned short* __restrict__ xt, unsigned short* __restrict__ wt) {
    int b = blockIdx.x;
    int t = threadIdx.x;
    if (b >= NB * H) {                        // ---- weight part ----
        int idx = (b - NB * H) * 256 + t;
        if (idx < KK * COUT * CIN) {
            int kk = idx / (COUT * CIN);
            int r  = idx - kk * (COUT * CIN);
            int co = r >> 7;
            int c  = r & 127;
            wt[idx] = f2bf(w[(co * CIN + c) * KK + kk]);
        }
        return;
    }
    // ---- x-transpose part: one (n,y) row per block; n = b&7 matches deform's XCD map ----
    __shared__ float tile[CIN][W + 4];
    int n = b & 7, y = b >> 3;
    const float* src = x + ((size_t)n * CIN * H + y) * W;
    #pragma unroll
    for (int it = 0; it < 8; ++it) {
        int idx = it * 256 + t;               // 0..2047 float4s
        int c  = idx >> 4;
        int x4 = (idx & 15) << 2;
        int xs = (x4 + ((c >> 5) << 4)) & 63; // rotate-swizzle per 32-ch group
        *(float4*)&tile[c][xs] = *(const float4*)(src + (size_t)c * H * W + x4);
    }
    __syncthreads();
    int xp = t >> 2;                          // x position 0..63
    int cbch = (t & 3) << 5;                  // channel base (32-ch chunk)
    int xr = (xp + ((cbch >> 5) << 4)) & 63;
    unsigned short* dst = xt + (((size_t)(n * H + y) * W + xp) * CIN + cbch);
    unsigned rr[16];
    #pragma unroll
    for (int i = 0; i < 16; ++i)
        rr[i] = cvt_pk_bf16(tile[cbch + 2 * i][xr], tile[cbch + 2 * i + 1][xr]);
    #pragma unroll
    for (int i = 0; i < 4; ++i)
        ((uint4*)dst)[i] = make_uint4(rr[4*i], rr[4*i+1], rr[4*i+2], rr[4*i+3]);
}

struct GatherCtx {
    const unsigned short *c00, *c01, *c10, *c11;
    float w00, w01, w10, w11;
};

__device__ __forceinline__ GatherCtx gather_setup(float dy, float dx, int ho, int wo, int kk,
                                                  const unsigned short* xbase) {
    GatherCtx g;
    float py = (float)(ho - 1 + kk / 3) + dy;
    float px = (float)(wo - 1 + kk % 3) + dx;
    float y0f = floorf(py), x0f = floorf(px);
    float wy1 = py - y0f, wx1 = px - x0f;
    float wy0 = 1.f - wy1, wx0 = 1.f - wx1;
    int y0 = (int)y0f, x0 = (int)x0f;
    int y1 = y0 + 1, x1 = x0 + 1;
    bool vy0 = (unsigned)y0 < (unsigned)H, vy1 = (unsigned)y1 < (unsigned)H;
    bool vx0 = (unsigned)x0 < (unsigned)W, vx1 = (unsigned)x1 < (unsigned)W;
    g.w00 = (vy0 && vx0) ? wy0 * wx0 : 0.f;
    g.w01 = (vy0 && vx1) ? wy0 * wx1 : 0.f;
    g.w10 = (vy1 && vx0) ? wy1 * wx0 : 0.f;
    g.w11 = (vy1 && vx1) ? wy1 * wx1 : 0.f;
    int yc0 = min(max(y0, 0), H - 1), yc1 = min(max(y1, 0), H - 1);
    int xc0 = min(max(x0, 0), W - 1), xc1 = min(max(x1, 0), W - 1);
    const unsigned short* r0 = xbase + (size_t)yc0 * W * CIN;
    const unsigned short* r1 = xbase + (size_t)yc1 * W * CIN;
    g.c00 = r0 + xc0 * CIN;  g.c01 = r0 + xc1 * CIN;
    g.c10 = r1 + xc0 * CIN;  g.c11 = r1 + xc1 * CIN;
    return g;
}

__device__ __forceinline__ void gather_issue(const GatherCtx& g, uint4* gv) {
    #pragma unroll
    for (int j = 0; j < 4; ++j) {            // 4 x 8-channel chunks = 32 ch/thread
        gv[4*j+0] = *(const uint4*)(g.c00 + 8*j);
        gv[4*j+1] = *(const uint4*)(g.c01 + 8*j);
        gv[4*j+2] = *(const uint4*)(g.c10 + 8*j);
        gv[4*j+3] = *(const uint4*)(g.c11 + 8*j);
    }
}

__device__ __forceinline__ void gather_blend_store(const GatherCtx& g, const uint4* gv,
                                                   unsigned short* dst) {
    #pragma unroll
    for (int j = 0; j < 4; ++j) {
        const unsigned* a0 = (const unsigned*)&gv[4*j+0];
        const unsigned* a1 = (const unsigned*)&gv[4*j+1];
        const unsigned* a2 = (const unsigned*)&gv[4*j+2];
        const unsigned* a3 = (const unsigned*)&gv[4*j+3];
        unsigned rr[4];
        #pragma unroll
        for (int i = 0; i < 4; ++i) {
            float v0 = g.w00*lo_f(a0[i]) + g.w01*lo_f(a1[i]) + g.w10*lo_f(a2[i]) + g.w11*lo_f(a3[i]);
            float v1 = g.w00*hi_f(a0[i]) + g.w01*hi_f(a1[i]) + g.w10*hi_f(a2[i]) + g.w11*hi_f(a3[i]);
            rr[i] = cvt_pk_bf16(v0, v1);
        }
        *(uint4*)(dst + 8*j) = make_uint4(rr[0], rr[1], rr[2], rr[3]);
    }
}

// Load this wave's B-fragments for kernel-tap kkv into a register bank (8 x b128).
#define LOADB(dst, kkv) { \
    const unsigned short* wk_ = wlane + ((size_t)(kkv) << 14); /* kk*COUT*CIN */ \
    _Pragma("unroll") \
    for (int nt_ = 0; nt_ < 2; ++nt_) \
        _Pragma("unroll") \
        for (int ct_ = 0; ct_ < 4; ++ct_) \
            dst[nt_][ct_] = *(const bf16x8*)(wk_ + (nt_ << 11) + (ct_ << 5)); }

#define MFMA_PHASE(PAR, BREG) { \
    _Pragma("unroll") \
    for (int ct_ = 0; ct_ < 4; ++ct_) { \
        bf16x8 a_[4]; \
        _Pragma("unroll") \
        for (int mt_ = 0; mt_ < 4; ++mt_) \
            a_[mt_] = *(const bf16x8*)&samp[PAR][lm + (mt_ << 4)][(ct_ << 5) + (lq << 3)]; \
        _Pragma("unroll") \
        for (int mt_ = 0; mt_ < 4; ++mt_) { \
            acc[mt_][0] = __builtin_amdgcn_mfma_f32_16x16x32_bf16(a_[mt_], BREG[0][ct_], acc[mt_][0], 0, 0, 0); \
            acc[mt_][1] = __builtin_amdgcn_mfma_f32_16x16x32_bf16(a_[mt_], BREG[1][ct_], acc[mt_][1], 0, 0, 0); } } }

// One iteration: issue kk+1 gathers + B(kk+1) loads (pinned above MFMA), MFMA(kk),
// blend+write samp[(kk+1)&1], barrier. LAST is a compile-time flag.
#define ITER(kkv, PAR, BCUR, BNXT, LAST) { \
    GatherCtx g_; uint4 gv_[16]; \
    if (!(LAST)) { \
        g_ = gather_setup(dyA, dxA, ho, p, (kkv) + 1, xbase); \
        gather_issue(g_, gv_); \
        LOADB(BNXT, (kkv) + 1); \
        if ((kkv) < KK - 2) { \
            dyA = offbase[(size_t)(2 * ((kkv) + 2)) * H * W]; \
            dxA = offbase[(size_t)(2 * ((kkv) + 2) + 1) * H * W]; \
        } \
    } \
    __builtin_amdgcn_sched_barrier(0); /* keep load issue above the MFMAs */ \
    MFMA_PHASE(PAR, BCUR); \
    if (!(LAST)) { \
        gather_blend_store(g_, gv_, &samp[1 - (PAR)][p][cb]); \
        __syncthreads(); \
    } }

// One block per (n, ho); n = bid&7 (XCD-local), ho = bid>>3. 256 threads = 4 waves.
// Wave wv: all 64 wo x couts wv*32..+31 (4 m-subtiles x 2 n-subtiles of 16x16x32).
__global__ __launch_bounds__(256, 2) void deform_main(
        const float* __restrict__ offs, const unsigned short* __restrict__ xt,
        const unsigned short* __restrict__ wt, float* __restrict__ out) {
    // +8 bf16 pad per row -> row stride 272B (68 words == 4 mod 32): uniform bank use on b128
    __shared__ __attribute__((aligned(16))) unsigned short samp[2][64][SROW];  // 69,632 B

    int b = blockIdx.x;
    int n = b & 7, ho = b >> 3;
    int t = threadIdx.x;
    int lane = t & 63, wv = t >> 6;
    int lm = lane & 15, lq = lane >> 4;
    int cobase = wv << 5;

    f32x4 acc[4][2];
    #pragma unroll
    for (int mt = 0; mt < 4; ++mt)
        #pragma unroll
        for (int nt = 0; nt < 2; ++nt) acc[mt][nt] = f32x4{0.f, 0.f, 0.f, 0.f};

    // sampling map: thread -> (position p = wo in 0..63, 32-channel chunk cb)
    int p  = t >> 2;
    int cb = (t & 3) << 5;
    const float* offbase = offs + (size_t)n * 2 * KK * H * W + (size_t)ho * W + p;
    const unsigned short* xbase = xt + (size_t)n * H * W * CIN + cb;
    // per-lane B-fragment base: frag(kk,nt,ct) at wt[(kk*COUT + cobase + nt*16 + lm)*CIN + ct*32 + lq*8]
    const unsigned short* wlane = wt + (((size_t)(cobase + lm)) << 7) + (lq << 3);

    bf16x8 bA[2][4], bB[2][4];   // double-buffered B-fragment register banks

    // ---- prologue: gather kk=0 + B0 into bA; write samp[0]; barrier ----
    float dyA = offbase[0];
    float dxA = offbase[(size_t)H * W];
    {
        GatherCtx g = gather_setup(dyA, dxA, ho, p, 0, xbase);
        uint4 gv[16];
        gather_issue(g, gv);
        LOADB(bA, 0);
        dyA = offbase[(size_t)2 * H * W];
        dxA = offbase[(size_t)3 * H * W];
        gather_blend_store(g, gv, &samp[0][p][cb]);
        __syncthreads();
    }

    for (int k2 = 0; k2 < 4; ++k2) {
        int kk = k2 << 1;
        ITER(kk,     0, bA, bB, false);
        ITER(kk + 1, 1, bB, bA, false);
    }
    ITER(8, 0, bA, bB, true);

    // epilogue: D[m = mt*16 + lq*4 + j][n = lm] -> out[n][co][ho][wo], float4 over wo
    #pragma unroll
    for (int mt = 0; mt < 4; ++mt) {
        int wob = (mt << 4) + (lq << 2);
        #pragma unroll
        for (int nt = 0; nt < 2; ++nt) {
            int co = cobase + (nt << 4) + lm;
            *(f32x4*)(out + (((size_t)(n * COUT + co) * H + ho) * W + wob)) = acc[mt][nt];
        }
    }
}

extern "C" void kernel_launch(void* const* d_in, const int* in_sizes, int n_in,
                              void* d_out, int out_size, void* d_ws, size_t ws_size,
                              hipStream_t stream) {
    const float* x      = (const float*)d_in[0];   // (8,128,64,64)
    const float* offset = (const float*)d_in[1];   // (8,18,64,64)
    const float* weight = (const float*)d_in[2];   // (128,128,3,3)
    float* out = (float*)d_out;

    unsigned short* xt = (unsigned short*)d_ws;                                  // 8 MB
    unsigned short* wt = (unsigned short*)((char*)d_ws + (size_t)NB*H*W*CIN*2);  // 288 KB

    int wblocks = (KK * COUT * CIN + 255) / 256;   // 576
    hipLaunchKernelGGL(prep_all, dim3(NB * H + wblocks), dim3(256), 0, stream,
                       x, weight, xt, wt);
    hipLaunchKernelGGL(deform_main, dim3(NB * H), dim3(256), 0, stream,
                       offset, xt, wt, out);
}